// Round 15
// baseline (382.629 us; speedup 1.0000x reference)
//
#include <hip/hip_runtime.h>
#include <hip/hip_bf16.h>
#include <cstdint>
#include <cstddef>

#define NN 50000
#define RR 4
#define EE 400000
#define TE (RR*EE)
#define HR 25000         // hist bins per range (2 ranges * 25000 = 50000); 50KB LDS
#define RN (RR*NN)       // 200000
#define NSEG (NN*RR)     // 200000 (d-major, r-minor segments)
#define SCB2 782         // ceil(NSEG/256)
#define NBK 512          // dst buckets for the partition
#define BKSZ 98          // nodes per bucket (512*98 >= 50000)
#define CHA 4000         // edges per phase-A block (100 chunks/relation)
#define MAXSPAN 4608     // LDS image capacity (avg span ~3136)

using frag_ab = __attribute__((ext_vector_type(8))) short;   // 8 bf16 (4 VGPRs)
using frag_cd = __attribute__((ext_vector_type(4))) float;   // 4 fp32

static __device__ __forceinline__ unsigned short f2bf(float f) {
    union { float f; unsigned u; } v; v.f = f;
    unsigned r = (v.u + 0x7FFF + ((v.u >> 16) & 1)) >> 16;   // RNE
    return (unsigned short)r;
}
static __device__ __forceinline__ unsigned pack2(float lo, float hi) {
    return (unsigned)f2bf(lo) | ((unsigned)f2bf(hi) << 16);
}
static __device__ __forceinline__ float blo(unsigned u) { return __uint_as_float(u << 16); }
static __device__ __forceinline__ float bhi(unsigned u) { return __uint_as_float(u & 0xFFFF0000u); }

// ---------------- k_pre: degree histograms + x/basis converts (one launch) ----
// Hist split 64 -> 128 blocks: each (r,side,range) covers 8 chunks of EE/8
// ints; chunks qc and qc+4 share slab (qc&3) via global atomicAdd into
// hipMemsetAsync-zeroed cnt buffers. 2x CU coverage for the ~3.2M LDS-atomic
// phase. blocks [0,128): hist; [128,1691): x->bf16; [1691,1771): Bt.
__global__ __launch_bounds__(1024) void k_pre(const int* __restrict__ src,
                                              const int* __restrict__ dst,
                                              int* __restrict__ cnt_srcQ,
                                              int* __restrict__ cnt_dstQ,
                                              const float4* __restrict__ x4,
                                              uint2* __restrict__ o,
                                              const float* __restrict__ B0,
                                              const float* __restrict__ B1,
                                              const float* __restrict__ B2,
                                              unsigned short* __restrict__ Bt0,
                                              unsigned short* __restrict__ Bt1,
                                              unsigned short* __restrict__ Bt2) {
    __shared__ unsigned bins[HR / 2];   // 12500 uints = 50 KB
    int bid = blockIdx.x;
    if (bid < 128) {
        int combo = bid >> 4;           // 0..7 : (r, side)
        int range = (bid >> 3) & 1;     // 0..1
        int qc    = bid & 7;            // 0..7 chunk
        int r = combo >> 1;
        int side = combo & 1;
        const int* arr = (side == 0 ? src : dst) + (size_t)r * EE + (size_t)qc * (EE / 8);
        int lo = range * HR;
        for (int i = threadIdx.x; i < HR / 2; i += 1024) bins[i] = 0;
        __syncthreads();
        const int4* a4 = (const int4*)arr;
        for (int i = threadIdx.x; i < EE / 32; i += 1024) {
            int4 v = a4[i];
            int t;
            t = v.x - lo; if ((unsigned)t < (unsigned)HR) atomicAdd(&bins[t >> 1], 1u << ((t & 1) * 16));
            t = v.y - lo; if ((unsigned)t < (unsigned)HR) atomicAdd(&bins[t >> 1], 1u << ((t & 1) * 16));
            t = v.z - lo; if ((unsigned)t < (unsigned)HR) atomicAdd(&bins[t >> 1], 1u << ((t & 1) * 16));
            t = v.w - lo; if ((unsigned)t < (unsigned)HR) atomicAdd(&bins[t >> 1], 1u << ((t & 1) * 16));
        }
        __syncthreads();
        int* outp = (side == 0 ? cnt_srcQ : cnt_dstQ) + (size_t)(qc & 3) * RN + (size_t)r * NN + lo;
        for (int i = threadIdx.x; i < HR / 2; i += 1024) {
            unsigned b = bins[i];
            unsigned lo16 = b & 0xFFFFu, hi16 = b >> 16;
            if (lo16) atomicAdd(&outp[2 * i], (int)lo16);
            if (hi16) atomicAdd(&outp[2 * i + 1], (int)hi16);
        }
    } else if (bid < 1691) {
        int i = (bid - 128) * 1024 + threadIdx.x;
        if (i < NN * 32) {
            float4 v = x4[i];
            o[i] = make_uint2(pack2(v.x, v.y), pack2(v.z, v.w));
        }
    } else {
        int t = (bid - 1691) * 1024 + threadIdx.x;   // [0, 81920)
        if (t < 32768) {
            int k = t & 255, n = t >> 8;
            Bt0[t] = f2bf(B0[k * 128 + n]);
        } else if (t < 65536) {
            int i = t - 32768;
            int k = i & 255, n = i >> 8;
            Bt1[i] = f2bf(B1[k * 128 + n]);
        } else {
            int i = t - 65536;
            int k = i & 255, n = i >> 8;
            Bt2[i] = f2bf(B2[k * 64 + n]);
        }
    }
}

// ---------------- k_norms_partial: norms + cntd2 + per-block partial sums ----
__global__ __launch_bounds__(256) void k_norms_partial(const int* __restrict__ cnt_srcQ,
                                                       const int* __restrict__ cnt_dstQ,
                                                       float* __restrict__ nsrc,
                                                       float* __restrict__ ndst,
                                                       int* __restrict__ cntd2,
                                                       int* __restrict__ part) {
    __shared__ int s[256];
    int t = threadIdx.x;
    int f = blockIdx.x * 256 + t;
    int v = 0;
    if (f < NSEG) {
        int d = f >> 2, r = f & 3;
        int i = r * NN + d;
        int ss = cnt_srcQ[i] + cnt_srcQ[RN + i] + cnt_srcQ[2 * RN + i] + cnt_srcQ[3 * RN + i];
        int ds = cnt_dstQ[i] + cnt_dstQ[RN + i] + cnt_dstQ[2 * RN + i] + cnt_dstQ[3 * RN + i];
        nsrc[i] = 1.0f / sqrtf(fmaxf((float)ss, 1.0f));
        ndst[i] = 1.0f / sqrtf(fmaxf((float)ds, 1.0f));
        cntd2[f] = ds;
        v = ds;
    }
    s[t] = v;
    __syncthreads();
    for (int off = 128; off > 0; off >>= 1) {
        if (t < off) s[t] += s[t + off];
        __syncthreads();
    }
    if (t == 0) part[blockIdx.x] = s[0];
}

// ---------------- k_emit2: block-prefix + scan + rp2 + gcur (R9-validated) ----
__global__ __launch_bounds__(256) void k_emit2(const int* __restrict__ cntd2,
                                               const int* __restrict__ part,
                                               int* __restrict__ rp2,
                                               int* __restrict__ gcur) {
    __shared__ int red[256];
    __shared__ int s[256];
    int t = threadIdx.x;
    int bid = blockIdx.x;
    int acc = 0;
    for (int j = t; j < bid; j += 256) acc += part[j];
    red[t] = acc;
    __syncthreads();
    for (int off = 128; off > 0; off >>= 1) {
        if (t < off) red[t] += red[t + off];
        __syncthreads();
    }
    int offs0 = red[0];
    __syncthreads();
    int f = bid * 256 + t;
    int v = (f < NSEG) ? cntd2[f] : 0;
    s[t] = v;
    __syncthreads();
    for (int off = 1; off < 256; off <<= 1) {
        int u = (t >= off) ? s[t - off] : 0;
        __syncthreads();
        s[t] += u;
        __syncthreads();
    }
    if (f < NSEG) {
        int rv = offs0 + s[t] - v;
        rp2[f] = rv;
        if (f % (BKSZ * 4) == 0) gcur[f / (BKSZ * 4)] = rv;
    }
    if (f == NSEG - 1) {
        rp2[NSEG] = TE;
        gcur[NBK - 1] = TE;
    }
}

// ---------------- two-phase edge partition (validated) ----------
__global__ __launch_bounds__(256) void k_fillA(const int* __restrict__ src,
                                               const int* __restrict__ dst,
                                               int* __restrict__ gcur,
                                               unsigned* __restrict__ stage) {
    __shared__ int cnt[NBK];
    __shared__ int rcur[NBK];
    int r = blockIdx.y;
    int base_e = blockIdx.x * CHA;
    int t = threadIdx.x;
    for (int i = t; i < NBK; i += 256) cnt[i] = 0;
    __syncthreads();
    const int* dr = dst + (size_t)r * EE;
    const int* sr = src + (size_t)r * EE;
    for (int i = base_e + t; i < base_e + CHA; i += 256) {
        int d = dr[i];
        atomicAdd(&cnt[d / BKSZ], 1);
    }
    __syncthreads();
    for (int i = t; i < NBK; i += 256) rcur[i] = atomicAdd(&gcur[i], cnt[i]);
    __syncthreads();
    for (int i = base_e + t; i < base_e + CHA; i += 256) {
        int d = dr[i];
        int s = sr[i];
        int b = d / BKSZ;
        int dl = d - b * BKSZ;
        int pos = atomicAdd(&rcur[b], 1);
        stage[pos] = (unsigned)s | ((unsigned)r << 16) | ((unsigned)dl << 18);
    }
}

__global__ __launch_bounds__(256) void k_fillB(const unsigned* __restrict__ stage,
                                               const int* __restrict__ rp2,
                                               const float* __restrict__ nsrc,
                                               const float* __restrict__ ndst,
                                               uint2* __restrict__ ed) {
    __shared__ unsigned imgU[MAXSPAN];
    __shared__ float imgW[MAXSPAN];
    __shared__ int lcur[BKSZ * 4];
    __shared__ float ndL[BKSZ * 4];
    int b = blockIdx.x;
    int t = threadIdx.x;
    int node0 = b * BKSZ;
    if (node0 >= NN) return;
    int nodes = min(BKSZ, NN - node0);
    int nseg_local = nodes * 4;
    int segbase = node0 * 4;
    for (int i = t; i < nseg_local; i += 256) {
        lcur[i] = rp2[segbase + i];
        ndL[i] = ndst[(i & 3) * NN + node0 + (i >> 2)];
    }
    __syncthreads();
    int S0 = rp2[segbase];
    int S1 = rp2[segbase + nseg_local];
    int span = S1 - S0;
    if (span <= MAXSPAN) {
        for (int i = S0 + t; i < S1; i += 256) {
            unsigned w = stage[i];
            int s = (int)(w & 0xFFFFu);
            int r = (int)((w >> 16) & 3u);
            int dl = (int)(w >> 18);
            int seg = dl * 4 + r;
            int pos = atomicAdd(&lcur[seg], 1);
            int idx = pos - S0;
            imgU[idx] = w & 0x3FFFFu;
            imgW[idx] = nsrc[r * NN + s] * ndL[seg];
        }
        __syncthreads();
        for (int i = t; i < span; i += 256)
            ed[S0 + i] = make_uint2(imgU[i], __float_as_uint(imgW[i]));
    } else {
        for (int i = S0 + t; i < S1; i += 256) {
            unsigned w = stage[i];
            int s = (int)(w & 0xFFFFu);
            int r = (int)((w >> 16) & 3u);
            int dl = (int)(w >> 18);
            int seg = dl * 4 + r;
            int pos = atomicAdd(&lcur[seg], 1);
            ed[pos] = make_uint2(w & 0x3FFFFu,
                                 __float_as_uint(nsrc[r * NN + s] * ndL[seg]));
        }
    }
}

// ---------------- FUSED aggregation + GEMM, 512 threads (R7-exact, 84.0us) ---
// Measured fused ladder: 512t/32n = 84.0 < 256t/16n = 87.7 < dynamic = 89.0.
// Larger blocks amortize the GEMM tail best; balance knobs are dead (R9/R13).
template <int BN, bool BF16OUT>
__global__ __launch_bounds__(512) void k_agg_gemm(const uint4* __restrict__ hb4,
                                                  const int* __restrict__ rp2,
                                                  const uint2* __restrict__ ed,
                                                  const float* __restrict__ coeff,
                                                  const unsigned short* __restrict__ Bt,
                                                  void* __restrict__ Cout) {
    __shared__ uint4 ldsA4[32 * 32];   // 16 KB: 32 rows x 512B
    char* ldsB = (char*)ldsA4;

    int w = threadIdx.x >> 6;          // wave 0..7
    int lane = threadIdx.x & 63;
    int q = lane >> 4, hl = lane & 15;
    int node0 = blockIdx.x * 32;

    float c00 = coeff[0], c01 = coeff[1], c10 = coeff[2], c11 = coeff[3];
    float c20 = coeff[4], c21 = coeff[5], c30 = coeff[6], c31 = coeff[7];

#pragma unroll 1
    for (int k4 = 0; k4 < 4; k4++) {
        int rowl = w + k4 * 8;          // local row 0..31
        int node = node0 + rowl;
        if (node < NN) {                // wave-uniform guard
            float a00 = 0.f, a01 = 0.f, a02 = 0.f, a03 = 0.f;
            float a04 = 0.f, a05 = 0.f, a06 = 0.f, a07 = 0.f;
            float a10 = 0.f, a11 = 0.f, a12 = 0.f, a13 = 0.f;
            float a14 = 0.f, a15 = 0.f, a16 = 0.f, a17 = 0.f;

            int e0 = rp2[node * 4], e1 = rp2[node * 4 + 4];
            int e = e0;
            uint2 wA = make_uint2(0u, 0u), wB = make_uint2(0u, 0u);
            if (e + 7 < e1) { wA = ed[e + q]; wB = ed[e + 4 + q]; }
            for (; e + 7 < e1; e += 8) {
                uint4 hA = hb4[(size_t)(wA.x & 0xFFFFu) * 16 + hl];
                uint4 hB = hb4[(size_t)(wB.x & 0xFFFFu) * 16 + hl];
                int eN = (e + 15 < e1) ? (e + 8) : e0;
                uint2 nA = ed[eN + q];
                uint2 nB = ed[eN + 4 + q];

                int rA = (int)(wA.x >> 16);
                int rB = (int)(wB.x >> 16);
                float wsA = __uint_as_float(wA.y);
                float wsB = __uint_as_float(wB.y);
                float wa0 = (rA == 0 ? c00 : rA == 1 ? c10 : rA == 2 ? c20 : c30) * wsA;
                float wa1 = (rA == 0 ? c01 : rA == 1 ? c11 : rA == 2 ? c21 : c31) * wsA;
                float wb0 = (rB == 0 ? c00 : rB == 1 ? c10 : rB == 2 ? c20 : c30) * wsB;
                float wb1 = (rB == 0 ? c01 : rB == 1 ? c11 : rB == 2 ? c21 : c31) * wsB;

                float h0 = blo(hA.x), h1 = bhi(hA.x), h2 = blo(hA.y), h3 = bhi(hA.y);
                float h4 = blo(hA.z), h5 = bhi(hA.z), h6 = blo(hA.w), h7 = bhi(hA.w);
                a00 += wa0 * h0; a01 += wa0 * h1; a02 += wa0 * h2; a03 += wa0 * h3;
                a04 += wa0 * h4; a05 += wa0 * h5; a06 += wa0 * h6; a07 += wa0 * h7;
                a10 += wa1 * h0; a11 += wa1 * h1; a12 += wa1 * h2; a13 += wa1 * h3;
                a14 += wa1 * h4; a15 += wa1 * h5; a16 += wa1 * h6; a17 += wa1 * h7;

                h0 = blo(hB.x); h1 = bhi(hB.x); h2 = blo(hB.y); h3 = bhi(hB.y);
                h4 = blo(hB.z); h5 = bhi(hB.z); h6 = blo(hB.w); h7 = bhi(hB.w);
                a00 += wb0 * h0; a01 += wb0 * h1; a02 += wb0 * h2; a03 += wb0 * h3;
                a04 += wb0 * h4; a05 += wb0 * h5; a06 += wb0 * h6; a07 += wb0 * h7;
                a10 += wb1 * h0; a11 += wb1 * h1; a12 += wb1 * h2; a13 += wb1 * h3;
                a14 += wb1 * h4; a15 += wb1 * h5; a16 += wb1 * h6; a17 += wb1 * h7;

                wA = nA; wB = nB;
            }
            for (; e < e1; e += 4) {    // masked tail: 1 edge/quarter
                int E = e + q;
                bool act = E < e1;
                uint2 weA = ed[act ? E : e0];
                uint4 hA = hb4[(size_t)(weA.x & 0xFFFFu) * 16 + hl];
                int rA = (int)(weA.x >> 16);
                float wsA = act ? __uint_as_float(weA.y) : 0.f;
                float wa0 = (rA == 0 ? c00 : rA == 1 ? c10 : rA == 2 ? c20 : c30) * wsA;
                float wa1 = (rA == 0 ? c01 : rA == 1 ? c11 : rA == 2 ? c21 : c31) * wsA;
                float h0 = blo(hA.x), h1 = bhi(hA.x), h2 = blo(hA.y), h3 = bhi(hA.y);
                float h4 = blo(hA.z), h5 = bhi(hA.z), h6 = blo(hA.w), h7 = bhi(hA.w);
                a00 += wa0 * h0; a01 += wa0 * h1; a02 += wa0 * h2; a03 += wa0 * h3;
                a04 += wa0 * h4; a05 += wa0 * h5; a06 += wa0 * h6; a07 += wa0 * h7;
                a10 += wa1 * h0; a11 += wa1 * h1; a12 += wa1 * h2; a13 += wa1 * h3;
                a14 += wa1 * h4; a15 += wa1 * h5; a16 += wa1 * h6; a17 += wa1 * h7;
            }

            // cross-quarter reduce (xor 16, then 32)
            a00 += __shfl_xor(a00, 16, 64); a00 += __shfl_xor(a00, 32, 64);
            a01 += __shfl_xor(a01, 16, 64); a01 += __shfl_xor(a01, 32, 64);
            a02 += __shfl_xor(a02, 16, 64); a02 += __shfl_xor(a02, 32, 64);
            a03 += __shfl_xor(a03, 16, 64); a03 += __shfl_xor(a03, 32, 64);
            a04 += __shfl_xor(a04, 16, 64); a04 += __shfl_xor(a04, 32, 64);
            a05 += __shfl_xor(a05, 16, 64); a05 += __shfl_xor(a05, 32, 64);
            a06 += __shfl_xor(a06, 16, 64); a06 += __shfl_xor(a06, 32, 64);
            a07 += __shfl_xor(a07, 16, 64); a07 += __shfl_xor(a07, 32, 64);
            a10 += __shfl_xor(a10, 16, 64); a10 += __shfl_xor(a10, 32, 64);
            a11 += __shfl_xor(a11, 16, 64); a11 += __shfl_xor(a11, 32, 64);
            a12 += __shfl_xor(a12, 16, 64); a12 += __shfl_xor(a12, 32, 64);
            a13 += __shfl_xor(a13, 16, 64); a13 += __shfl_xor(a13, 32, 64);
            a14 += __shfl_xor(a14, 16, 64); a14 += __shfl_xor(a14, 32, 64);
            a15 += __shfl_xor(a15, 16, 64); a15 += __shfl_xor(a15, 32, 64);
            a16 += __shfl_xor(a16, 16, 64); a16 += __shfl_xor(a16, 32, 64);
            a17 += __shfl_xor(a17, 16, 64); a17 += __shfl_xor(a17, 32, 64);

            // lane (q,hl): c = q>>1, h4 = q&1 -> channels hl*8 + h4*4 + 0..3
            int c = q >> 1, h4 = q & 1;
            float v0 = c ? (h4 ? a14 : a10) : (h4 ? a04 : a00);
            float v1 = c ? (h4 ? a15 : a11) : (h4 ? a05 : a01);
            float v2 = c ? (h4 ? a16 : a12) : (h4 ? a06 : a02);
            float v3 = c ? (h4 ? a17 : a13) : (h4 ? a07 : a03);
            uint2 st;
            st.x = pack2(v0, v1);
            st.y = pack2(v2, v3);
            int idx8 = c * 32 + hl * 2 + h4;                       // 8B unit index
            int boff = rowl * 512 + ((idx8 * 8) ^ ((rowl & 7) << 4));
            *(uint2*)(ldsB + boff) = st;
        }
    }
    __syncthreads();

    // ---- GEMM phase: C[32,BN] = ldsA[32,256] @ Bt^T ----
    int strip = w & 1;                 // row strip 0..1 (16 rows each)
    int colgrp = w >> 1;               // 0..3
    int m = lane & 15, qq = lane >> 4;
    constexpr int NTW = BN / 64;       // col tiles per wave (2 for 128, 1 for 64)

    frag_cd acc[NTW];
#pragma unroll
    for (int t = 0; t < NTW; t++) acc[t] = (frag_cd){0.f, 0.f, 0.f, 0.f};

    int arow = strip * 16 + m;
#pragma unroll
    for (int kc = 0; kc < 8; kc++) {
        int aoff = arow * 512 + ((qq * 16 + kc * 64) ^ ((arow & 7) << 4));
        frag_ab a = *(const frag_ab*)(ldsB + aoff);
#pragma unroll
        for (int t = 0; t < NTW; t++) {
            int ct = colgrp * NTW + t;
            frag_ab b = *(const frag_ab*)(Bt + (size_t)(ct * 16 + m) * 256 + kc * 32 + qq * 8);
            acc[t] = __builtin_amdgcn_mfma_f32_16x16x32_bf16(a, b, acc[t], 0, 0, 0);
        }
    }

    int row0 = node0 + strip * 16;
#pragma unroll
    for (int t = 0; t < NTW; t++) {
#pragma unroll
        for (int i = 0; i < 4; i++) {
            int row = row0 + qq * 4 + i;
            if (row < NN) {
                int col = (colgrp * NTW + t) * 16 + m;
                float v = acc[t][i];
                if (BF16OUT) {
                    v = fmaxf(v, 0.f);
                    ((unsigned short*)Cout)[(size_t)row * BN + col] = f2bf(v);
                } else {
                    ((float*)Cout)[(size_t)row * BN + col] = v;
                }
            }
        }
    }
}

// ---------------- host ----------------

extern "C" void kernel_launch(void* const* d_in, const int* in_sizes, int n_in,
                              void* d_out, int out_size, void* d_ws, size_t ws_size,
                              hipStream_t stream) {
    const float* x      = (const float*)d_in[0];
    const int*   src    = (const int*)d_in[1];
    const int*   dst    = (const int*)d_in[2];
    const float* basis0 = (const float*)d_in[3];
    const float* coeff0 = (const float*)d_in[4];
    const float* basis1 = (const float*)d_in[5];
    const float* coeff1 = (const float*)d_in[6];
    const float* basis2 = (const float*)d_in[7];
    const float* coeff2 = (const float*)d_in[8];
    float* out = (float*)d_out;

    char* p = (char*)d_ws;
    auto alloc = [&](size_t bytes) {
        char* r = p;
        p += (bytes + 255) & ~(size_t)255;
        return r;
    };
    int*   cnt_srcQ = (int*)alloc((size_t)4 * RN * 4);
    int*   cnt_dstQ = (int*)alloc((size_t)4 * RN * 4);
    float* nsrc     = (float*)alloc((size_t)RN * 4);
    float* ndst     = (float*)alloc((size_t)RN * 4);
    int*   cntd2    = (int*)alloc((size_t)NSEG * 4);
    int*   rp2      = (int*)alloc((size_t)(NSEG + 1) * 4);
    int*   part     = (int*)alloc((size_t)SCB2 * 4);
    int*   gcur     = (int*)alloc((size_t)NBK * 4);
    unsigned* stage = (unsigned*)alloc((size_t)TE * 4);
    uint2* ed       = (uint2*)alloc((size_t)TE * 8);
    unsigned* Hb    = (unsigned*)alloc((size_t)NN * 64 * 4);        // bf16 [N][128]
    unsigned* Hb2   = (unsigned*)alloc((size_t)NN * 64 * 4);        // bf16 [N][128]
    unsigned* Xb    = (unsigned*)alloc((size_t)NN * 64 * 4);        // bf16 [N][128]
    unsigned short* Bt0 = (unsigned short*)alloc((size_t)128 * 256 * 2);
    unsigned short* Bt1 = (unsigned short*)alloc((size_t)128 * 256 * 2);
    unsigned short* Bt2 = (unsigned short*)alloc((size_t)64 * 256 * 2);

    // hist slabs are now accumulated with atomics (8 chunks -> 4 slabs): zero first
    hipMemsetAsync(cnt_srcQ, 0, (size_t)4 * RN * 4, stream);
    hipMemsetAsync(cnt_dstQ, 0, (size_t)4 * RN * 4, stream);

    // setup: 5 dispatches
    k_pre<<<1771, 1024, 0, stream>>>(src, dst, cnt_srcQ, cnt_dstQ,
                                     (const float4*)x, (uint2*)Xb,
                                     basis0, basis1, basis2, Bt0, Bt1, Bt2);
    k_norms_partial<<<SCB2, 256, 0, stream>>>(cnt_srcQ, cnt_dstQ, nsrc, ndst, cntd2, part);
    k_emit2<<<SCB2, 256, 0, stream>>>(cntd2, part, rp2, gcur);
    k_fillA<<<dim3(EE / CHA, RR), 256, 0, stream>>>(src, dst, gcur, stage);
    k_fillB<<<NBK, 256, 0, stream>>>(stage, rp2, nsrc, ndst, ed);

    int fusedBlocks = (NN + 31) / 32;   // 1563

    // layer 0: Xb -> Hb (relu, bf16)
    k_agg_gemm<128, true><<<fusedBlocks, 512, 0, stream>>>(
        (const uint4*)Xb, rp2, ed, coeff0, Bt0, Hb);
    // layer 1: Hb -> Hb2 (double-buffered: in-place would race)
    k_agg_gemm<128, true><<<fusedBlocks, 512, 0, stream>>>(
        (const uint4*)Hb, rp2, ed, coeff1, Bt1, Hb2);
    // layer 2: Hb2 -> out (fp32, no relu)
    k_agg_gemm<64, false><<<fusedBlocks, 512, 0, stream>>>(
        (const uint4*)Hb2, rp2, ed, coeff2, Bt2, out);
}

// Round 17
// 369.909 us; speedup vs baseline: 1.0344x; 1.0344x over previous
//
#include <hip/hip_runtime.h>
#include <hip/hip_bf16.h>
#include <cstdint>
#include <cstddef>

#define NN 50000
#define RR 4
#define EE 400000
#define TE (RR*EE)
#define HR 25000         // hist bins per range (2 ranges * 25000 = 50000); 50KB LDS
#define RN (RR*NN)       // 200000
#define NSEG (NN*RR)     // 200000 (d-major, r-minor segments)
#define SCB2 782         // ceil(NSEG/256)
#define NBK 512          // dst buckets for the partition
#define BKSZ 98          // nodes per bucket (512*98 >= 50000)
#define CHA 4000         // edges per phase-A block (100 chunks/relation)
#define MAXSPAN 4608     // LDS image capacity (avg span ~3136)

using frag_ab = __attribute__((ext_vector_type(8))) short;   // 8 bf16 (4 VGPRs)
using frag_cd = __attribute__((ext_vector_type(4))) float;   // 4 fp32

static __device__ __forceinline__ unsigned short f2bf(float f) {
    union { float f; unsigned u; } v; v.f = f;
    unsigned r = (v.u + 0x7FFF + ((v.u >> 16) & 1)) >> 16;   // RNE
    return (unsigned short)r;
}
static __device__ __forceinline__ unsigned pack2(float lo, float hi) {
    return (unsigned)f2bf(lo) | ((unsigned)f2bf(hi) << 16);
}
static __device__ __forceinline__ float blo(unsigned u) { return __uint_as_float(u << 16); }
static __device__ __forceinline__ float bhi(unsigned u) { return __uint_as_float(u & 0xFFFF0000u); }

// ---------------- k_pre: degree histograms + x/basis converts (one launch) ----
// R9-EXACT (remainder measured 113.5us). R15 lesson: splitting hist to 128
// blocks + global-atomic writeback COST ~19us (3.2M global atomics >> 1.6M
// plain stores) — reverted. blocks [0,64): hist; [64,1627): x; [1627,1707): Bt.
__global__ __launch_bounds__(1024) void k_pre(const int* __restrict__ src,
                                              const int* __restrict__ dst,
                                              int* __restrict__ cnt_srcQ,
                                              int* __restrict__ cnt_dstQ,
                                              const float4* __restrict__ x4,
                                              uint2* __restrict__ o,
                                              const float* __restrict__ B0,
                                              const float* __restrict__ B1,
                                              const float* __restrict__ B2,
                                              unsigned short* __restrict__ Bt0,
                                              unsigned short* __restrict__ Bt1,
                                              unsigned short* __restrict__ Bt2) {
    __shared__ unsigned bins[HR / 2];   // 12500 uints = 50 KB
    int bid = blockIdx.x;
    if (bid < 64) {
        int combo = bid >> 3;           // 0..7 : (r, side)
        int range = (bid >> 2) & 1;     // 0..1
        int qc    = bid & 3;            // 0..3
        int r = combo >> 1;
        int side = combo & 1;
        const int* arr = (side == 0 ? src : dst) + (size_t)r * EE + (size_t)qc * (EE / 4);
        int lo = range * HR;
        for (int i = threadIdx.x; i < HR / 2; i += 1024) bins[i] = 0;
        __syncthreads();
        const int4* a4 = (const int4*)arr;
        for (int i = threadIdx.x; i < EE / 16; i += 1024) {
            int4 v = a4[i];
            int t;
            t = v.x - lo; if ((unsigned)t < (unsigned)HR) atomicAdd(&bins[t >> 1], 1u << ((t & 1) * 16));
            t = v.y - lo; if ((unsigned)t < (unsigned)HR) atomicAdd(&bins[t >> 1], 1u << ((t & 1) * 16));
            t = v.z - lo; if ((unsigned)t < (unsigned)HR) atomicAdd(&bins[t >> 1], 1u << ((t & 1) * 16));
            t = v.w - lo; if ((unsigned)t < (unsigned)HR) atomicAdd(&bins[t >> 1], 1u << ((t & 1) * 16));
        }
        __syncthreads();
        int* outp = (side == 0 ? cnt_srcQ : cnt_dstQ) + (size_t)qc * RN + (size_t)r * NN + lo;
        for (int i = threadIdx.x; i < HR / 2; i += 1024) {
            unsigned b = bins[i];
            outp[2 * i]     = (int)(b & 0xFFFFu);
            outp[2 * i + 1] = (int)(b >> 16);
        }
    } else if (bid < 1627) {
        int i = (bid - 64) * 1024 + threadIdx.x;
        if (i < NN * 32) {
            float4 v = x4[i];
            o[i] = make_uint2(pack2(v.x, v.y), pack2(v.z, v.w));
        }
    } else {
        int t = (bid - 1627) * 1024 + threadIdx.x;   // [0, 81920)
        if (t < 32768) {
            int k = t & 255, n = t >> 8;
            Bt0[t] = f2bf(B0[k * 128 + n]);
        } else if (t < 65536) {
            int i = t - 32768;
            int k = i & 255, n = i >> 8;
            Bt1[i] = f2bf(B1[k * 128 + n]);
        } else {
            int i = t - 65536;
            int k = i & 255, n = i >> 8;
            Bt2[i] = f2bf(B2[k * 64 + n]);
        }
    }
}

// ---------------- k_norms_partial: norms + cntd2 + per-block partial sums ----
__global__ __launch_bounds__(256) void k_norms_partial(const int* __restrict__ cnt_srcQ,
                                                       const int* __restrict__ cnt_dstQ,
                                                       float* __restrict__ nsrc,
                                                       float* __restrict__ ndst,
                                                       int* __restrict__ cntd2,
                                                       int* __restrict__ part) {
    __shared__ int s[256];
    int t = threadIdx.x;
    int f = blockIdx.x * 256 + t;
    int v = 0;
    if (f < NSEG) {
        int d = f >> 2, r = f & 3;
        int i = r * NN + d;
        int ss = cnt_srcQ[i] + cnt_srcQ[RN + i] + cnt_srcQ[2 * RN + i] + cnt_srcQ[3 * RN + i];
        int ds = cnt_dstQ[i] + cnt_dstQ[RN + i] + cnt_dstQ[2 * RN + i] + cnt_dstQ[3 * RN + i];
        nsrc[i] = 1.0f / sqrtf(fmaxf((float)ss, 1.0f));
        ndst[i] = 1.0f / sqrtf(fmaxf((float)ds, 1.0f));
        cntd2[f] = ds;
        v = ds;
    }
    s[t] = v;
    __syncthreads();
    for (int off = 128; off > 0; off >>= 1) {
        if (t < off) s[t] += s[t + off];
        __syncthreads();
    }
    if (t == 0) part[blockIdx.x] = s[0];
}

// ---------------- k_emit2: block-prefix + scan + rp2 + gcur (R9-validated) ----
__global__ __launch_bounds__(256) void k_emit2(const int* __restrict__ cntd2,
                                               const int* __restrict__ part,
                                               int* __restrict__ rp2,
                                               int* __restrict__ gcur) {
    __shared__ int red[256];
    __shared__ int s[256];
    int t = threadIdx.x;
    int bid = blockIdx.x;
    int acc = 0;
    for (int j = t; j < bid; j += 256) acc += part[j];
    red[t] = acc;
    __syncthreads();
    for (int off = 128; off > 0; off >>= 1) {
        if (t < off) red[t] += red[t + off];
        __syncthreads();
    }
    int offs0 = red[0];
    __syncthreads();
    int f = bid * 256 + t;
    int v = (f < NSEG) ? cntd2[f] : 0;
    s[t] = v;
    __syncthreads();
    for (int off = 1; off < 256; off <<= 1) {
        int u = (t >= off) ? s[t - off] : 0;
        __syncthreads();
        s[t] += u;
        __syncthreads();
    }
    if (f < NSEG) {
        int rv = offs0 + s[t] - v;
        rp2[f] = rv;
        if (f % (BKSZ * 4) == 0) gcur[f / (BKSZ * 4)] = rv;
    }
    if (f == NSEG - 1) {
        rp2[NSEG] = TE;
        gcur[NBK - 1] = TE;
    }
}

// ---------------- two-phase edge partition (validated) ----------
__global__ __launch_bounds__(256) void k_fillA(const int* __restrict__ src,
                                               const int* __restrict__ dst,
                                               int* __restrict__ gcur,
                                               unsigned* __restrict__ stage) {
    __shared__ int cnt[NBK];
    __shared__ int rcur[NBK];
    int r = blockIdx.y;
    int base_e = blockIdx.x * CHA;
    int t = threadIdx.x;
    for (int i = t; i < NBK; i += 256) cnt[i] = 0;
    __syncthreads();
    const int* dr = dst + (size_t)r * EE;
    const int* sr = src + (size_t)r * EE;
    for (int i = base_e + t; i < base_e + CHA; i += 256) {
        int d = dr[i];
        atomicAdd(&cnt[d / BKSZ], 1);
    }
    __syncthreads();
    for (int i = t; i < NBK; i += 256) rcur[i] = atomicAdd(&gcur[i], cnt[i]);
    __syncthreads();
    for (int i = base_e + t; i < base_e + CHA; i += 256) {
        int d = dr[i];
        int s = sr[i];
        int b = d / BKSZ;
        int dl = d - b * BKSZ;
        int pos = atomicAdd(&rcur[b], 1);
        stage[pos] = (unsigned)s | ((unsigned)r << 16) | ((unsigned)dl << 18);
    }
}

__global__ __launch_bounds__(256) void k_fillB(const unsigned* __restrict__ stage,
                                               const int* __restrict__ rp2,
                                               const float* __restrict__ nsrc,
                                               const float* __restrict__ ndst,
                                               uint2* __restrict__ ed) {
    __shared__ unsigned imgU[MAXSPAN];
    __shared__ float imgW[MAXSPAN];
    __shared__ int lcur[BKSZ * 4];
    __shared__ float ndL[BKSZ * 4];
    int b = blockIdx.x;
    int t = threadIdx.x;
    int node0 = b * BKSZ;
    if (node0 >= NN) return;
    int nodes = min(BKSZ, NN - node0);
    int nseg_local = nodes * 4;
    int segbase = node0 * 4;
    for (int i = t; i < nseg_local; i += 256) {
        lcur[i] = rp2[segbase + i];
        ndL[i] = ndst[(i & 3) * NN + node0 + (i >> 2)];
    }
    __syncthreads();
    int S0 = rp2[segbase];
    int S1 = rp2[segbase + nseg_local];
    int span = S1 - S0;
    if (span <= MAXSPAN) {
        for (int i = S0 + t; i < S1; i += 256) {
            unsigned w = stage[i];
            int s = (int)(w & 0xFFFFu);
            int r = (int)((w >> 16) & 3u);
            int dl = (int)(w >> 18);
            int seg = dl * 4 + r;
            int pos = atomicAdd(&lcur[seg], 1);
            int idx = pos - S0;
            imgU[idx] = w & 0x3FFFFu;
            imgW[idx] = nsrc[r * NN + s] * ndL[seg];
        }
        __syncthreads();
        for (int i = t; i < span; i += 256)
            ed[S0 + i] = make_uint2(imgU[i], __float_as_uint(imgW[i]));
    } else {
        for (int i = S0 + t; i < S1; i += 256) {
            unsigned w = stage[i];
            int s = (int)(w & 0xFFFFu);
            int r = (int)((w >> 16) & 3u);
            int dl = (int)(w >> 18);
            int seg = dl * 4 + r;
            int pos = atomicAdd(&lcur[seg], 1);
            ed[pos] = make_uint2(w & 0x3FFFFu,
                                 __float_as_uint(nsrc[r * NN + s] * ndL[seg]));
        }
    }
}

// ---------------- FUSED aggregation + GEMM, 512 threads (measured 83.4us) ----
// Fused ladder: 512t/32n = 83.4-84.0 < 256t/16n = 87.7 < dynamic = 89.0.
template <int BN, bool BF16OUT>
__global__ __launch_bounds__(512) void k_agg_gemm(const uint4* __restrict__ hb4,
                                                  const int* __restrict__ rp2,
                                                  const uint2* __restrict__ ed,
                                                  const float* __restrict__ coeff,
                                                  const unsigned short* __restrict__ Bt,
                                                  void* __restrict__ Cout) {
    __shared__ uint4 ldsA4[32 * 32];   // 16 KB: 32 rows x 512B
    char* ldsB = (char*)ldsA4;

    int w = threadIdx.x >> 6;          // wave 0..7
    int lane = threadIdx.x & 63;
    int q = lane >> 4, hl = lane & 15;
    int node0 = blockIdx.x * 32;

    float c00 = coeff[0], c01 = coeff[1], c10 = coeff[2], c11 = coeff[3];
    float c20 = coeff[4], c21 = coeff[5], c30 = coeff[6], c31 = coeff[7];

#pragma unroll 1
    for (int k4 = 0; k4 < 4; k4++) {
        int rowl = w + k4 * 8;          // local row 0..31
        int node = node0 + rowl;
        if (node < NN) {                // wave-uniform guard
            float a00 = 0.f, a01 = 0.f, a02 = 0.f, a03 = 0.f;
            float a04 = 0.f, a05 = 0.f, a06 = 0.f, a07 = 0.f;
            float a10 = 0.f, a11 = 0.f, a12 = 0.f, a13 = 0.f;
            float a14 = 0.f, a15 = 0.f, a16 = 0.f, a17 = 0.f;

            int e0 = rp2[node * 4], e1 = rp2[node * 4 + 4];
            int e = e0;
            uint2 wA = make_uint2(0u, 0u), wB = make_uint2(0u, 0u);
            if (e + 7 < e1) { wA = ed[e + q]; wB = ed[e + 4 + q]; }
            for (; e + 7 < e1; e += 8) {
                uint4 hA = hb4[(size_t)(wA.x & 0xFFFFu) * 16 + hl];
                uint4 hB = hb4[(size_t)(wB.x & 0xFFFFu) * 16 + hl];
                int eN = (e + 15 < e1) ? (e + 8) : e0;
                uint2 nA = ed[eN + q];
                uint2 nB = ed[eN + 4 + q];

                int rA = (int)(wA.x >> 16);
                int rB = (int)(wB.x >> 16);
                float wsA = __uint_as_float(wA.y);
                float wsB = __uint_as_float(wB.y);
                float wa0 = (rA == 0 ? c00 : rA == 1 ? c10 : rA == 2 ? c20 : c30) * wsA;
                float wa1 = (rA == 0 ? c01 : rA == 1 ? c11 : rA == 2 ? c21 : c31) * wsA;
                float wb0 = (rB == 0 ? c00 : rB == 1 ? c10 : rB == 2 ? c20 : c30) * wsB;
                float wb1 = (rB == 0 ? c01 : rB == 1 ? c11 : rB == 2 ? c21 : c31) * wsB;

                float h0 = blo(hA.x), h1 = bhi(hA.x), h2 = blo(hA.y), h3 = bhi(hA.y);
                float h4 = blo(hA.z), h5 = bhi(hA.z), h6 = blo(hA.w), h7 = bhi(hA.w);
                a00 += wa0 * h0; a01 += wa0 * h1; a02 += wa0 * h2; a03 += wa0 * h3;
                a04 += wa0 * h4; a05 += wa0 * h5; a06 += wa0 * h6; a07 += wa0 * h7;
                a10 += wa1 * h0; a11 += wa1 * h1; a12 += wa1 * h2; a13 += wa1 * h3;
                a14 += wa1 * h4; a15 += wa1 * h5; a16 += wa1 * h6; a17 += wa1 * h7;

                h0 = blo(hB.x); h1 = bhi(hB.x); h2 = blo(hB.y); h3 = bhi(hB.y);
                h4 = blo(hB.z); h5 = bhi(hB.z); h6 = blo(hB.w); h7 = bhi(hB.w);
                a00 += wb0 * h0; a01 += wb0 * h1; a02 += wb0 * h2; a03 += wb0 * h3;
                a04 += wb0 * h4; a05 += wb0 * h5; a06 += wb0 * h6; a07 += wb0 * h7;
                a10 += wb1 * h0; a11 += wb1 * h1; a12 += wb1 * h2; a13 += wb1 * h3;
                a14 += wb1 * h4; a15 += wb1 * h5; a16 += wb1 * h6; a17 += wb1 * h7;

                wA = nA; wB = nB;
            }
            for (; e < e1; e += 4) {    // masked tail: 1 edge/quarter
                int E = e + q;
                bool act = E < e1;
                uint2 weA = ed[act ? E : e0];
                uint4 hA = hb4[(size_t)(weA.x & 0xFFFFu) * 16 + hl];
                int rA = (int)(weA.x >> 16);
                float wsA = act ? __uint_as_float(weA.y) : 0.f;
                float wa0 = (rA == 0 ? c00 : rA == 1 ? c10 : rA == 2 ? c20 : c30) * wsA;
                float wa1 = (rA == 0 ? c01 : rA == 1 ? c11 : rA == 2 ? c21 : c31) * wsA;
                float h0 = blo(hA.x), h1 = bhi(hA.x), h2 = blo(hA.y), h3 = bhi(hA.y);
                float h4 = blo(hA.z), h5 = bhi(hA.z), h6 = blo(hA.w), h7 = bhi(hA.w);
                a00 += wa0 * h0; a01 += wa0 * h1; a02 += wa0 * h2; a03 += wa0 * h3;
                a04 += wa0 * h4; a05 += wa0 * h5; a06 += wa0 * h6; a07 += wa0 * h7;
                a10 += wa1 * h0; a11 += wa1 * h1; a12 += wa1 * h2; a13 += wa1 * h3;
                a14 += wa1 * h4; a15 += wa1 * h5; a16 += wa1 * h6; a17 += wa1 * h7;
            }

            // cross-quarter reduce (xor 16, then 32)
            a00 += __shfl_xor(a00, 16, 64); a00 += __shfl_xor(a00, 32, 64);
            a01 += __shfl_xor(a01, 16, 64); a01 += __shfl_xor(a01, 32, 64);
            a02 += __shfl_xor(a02, 16, 64); a02 += __shfl_xor(a02, 32, 64);
            a03 += __shfl_xor(a03, 16, 64); a03 += __shfl_xor(a03, 32, 64);
            a04 += __shfl_xor(a04, 16, 64); a04 += __shfl_xor(a04, 32, 64);
            a05 += __shfl_xor(a05, 16, 64); a05 += __shfl_xor(a05, 32, 64);
            a06 += __shfl_xor(a06, 16, 64); a06 += __shfl_xor(a06, 32, 64);
            a07 += __shfl_xor(a07, 16, 64); a07 += __shfl_xor(a07, 32, 64);
            a10 += __shfl_xor(a10, 16, 64); a10 += __shfl_xor(a10, 32, 64);
            a11 += __shfl_xor(a11, 16, 64); a11 += __shfl_xor(a11, 32, 64);
            a12 += __shfl_xor(a12, 16, 64); a12 += __shfl_xor(a12, 32, 64);
            a13 += __shfl_xor(a13, 16, 64); a13 += __shfl_xor(a13, 32, 64);
            a14 += __shfl_xor(a14, 16, 64); a14 += __shfl_xor(a14, 32, 64);
            a15 += __shfl_xor(a15, 16, 64); a15 += __shfl_xor(a15, 32, 64);
            a16 += __shfl_xor(a16, 16, 64); a16 += __shfl_xor(a16, 32, 64);
            a17 += __shfl_xor(a17, 16, 64); a17 += __shfl_xor(a17, 32, 64);

            // lane (q,hl): c = q>>1, h4 = q&1 -> channels hl*8 + h4*4 + 0..3
            int c = q >> 1, h4 = q & 1;
            float v0 = c ? (h4 ? a14 : a10) : (h4 ? a04 : a00);
            float v1 = c ? (h4 ? a15 : a11) : (h4 ? a05 : a01);
            float v2 = c ? (h4 ? a16 : a12) : (h4 ? a06 : a02);
            float v3 = c ? (h4 ? a17 : a13) : (h4 ? a07 : a03);
            uint2 st;
            st.x = pack2(v0, v1);
            st.y = pack2(v2, v3);
            int idx8 = c * 32 + hl * 2 + h4;                       // 8B unit index
            int boff = rowl * 512 + ((idx8 * 8) ^ ((rowl & 7) << 4));
            *(uint2*)(ldsB + boff) = st;
        }
    }
    __syncthreads();

    // ---- GEMM phase: C[32,BN] = ldsA[32,256] @ Bt^T ----
    int strip = w & 1;                 // row strip 0..1 (16 rows each)
    int colgrp = w >> 1;               // 0..3
    int m = lane & 15, qq = lane >> 4;
    constexpr int NTW = BN / 64;       // col tiles per wave (2 for 128, 1 for 64)

    frag_cd acc[NTW];
#pragma unroll
    for (int t = 0; t < NTW; t++) acc[t] = (frag_cd){0.f, 0.f, 0.f, 0.f};

    int arow = strip * 16 + m;
#pragma unroll
    for (int kc = 0; kc < 8; kc++) {
        int aoff = arow * 512 + ((qq * 16 + kc * 64) ^ ((arow & 7) << 4));
        frag_ab a = *(const frag_ab*)(ldsB + aoff);
#pragma unroll
        for (int t = 0; t < NTW; t++) {
            int ct = colgrp * NTW + t;
            frag_ab b = *(const frag_ab*)(Bt + (size_t)(ct * 16 + m) * 256 + kc * 32 + qq * 8);
            acc[t] = __builtin_amdgcn_mfma_f32_16x16x32_bf16(a, b, acc[t], 0, 0, 0);
        }
    }

    int row0 = node0 + strip * 16;
#pragma unroll
    for (int t = 0; t < NTW; t++) {
#pragma unroll
        for (int i = 0; i < 4; i++) {
            int row = row0 + qq * 4 + i;
            if (row < NN) {
                int col = (colgrp * NTW + t) * 16 + m;
                float v = acc[t][i];
                if (BF16OUT) {
                    v = fmaxf(v, 0.f);
                    ((unsigned short*)Cout)[(size_t)row * BN + col] = f2bf(v);
                } else {
                    ((float*)Cout)[(size_t)row * BN + col] = v;
                }
            }
        }
    }
}

// ---------------- host ----------------

extern "C" void kernel_launch(void* const* d_in, const int* in_sizes, int n_in,
                              void* d_out, int out_size, void* d_ws, size_t ws_size,
                              hipStream_t stream) {
    const float* x      = (const float*)d_in[0];
    const int*   src    = (const int*)d_in[1];
    const int*   dst    = (const int*)d_in[2];
    const float* basis0 = (const float*)d_in[3];
    const float* coeff0 = (const float*)d_in[4];
    const float* basis1 = (const float*)d_in[5];
    const float* coeff1 = (const float*)d_in[6];
    const float* basis2 = (const float*)d_in[7];
    const float* coeff2 = (const float*)d_in[8];
    float* out = (float*)d_out;

    char* p = (char*)d_ws;
    auto alloc = [&](size_t bytes) {
        char* r = p;
        p += (bytes + 255) & ~(size_t)255;
        return r;
    };
    int*   cnt_srcQ = (int*)alloc((size_t)4 * RN * 4);
    int*   cnt_dstQ = (int*)alloc((size_t)4 * RN * 4);
    float* nsrc     = (float*)alloc((size_t)RN * 4);
    float* ndst     = (float*)alloc((size_t)RN * 4);
    int*   cntd2    = (int*)alloc((size_t)NSEG * 4);
    int*   rp2      = (int*)alloc((size_t)(NSEG + 1) * 4);
    int*   part     = (int*)alloc((size_t)SCB2 * 4);
    int*   gcur     = (int*)alloc((size_t)NBK * 4);
    unsigned* stage = (unsigned*)alloc((size_t)TE * 4);
    uint2* ed       = (uint2*)alloc((size_t)TE * 8);
    unsigned* Hb    = (unsigned*)alloc((size_t)NN * 64 * 4);        // bf16 [N][128]
    unsigned* Hb2   = (unsigned*)alloc((size_t)NN * 64 * 4);        // bf16 [N][128]
    unsigned* Xb    = (unsigned*)alloc((size_t)NN * 64 * 4);        // bf16 [N][128]
    unsigned short* Bt0 = (unsigned short*)alloc((size_t)128 * 256 * 2);
    unsigned short* Bt1 = (unsigned short*)alloc((size_t)128 * 256 * 2);
    unsigned short* Bt2 = (unsigned short*)alloc((size_t)64 * 256 * 2);

    // setup: 5 dispatches (R9-exact, remainder measured 113.5us)
    k_pre<<<1707, 1024, 0, stream>>>(src, dst, cnt_srcQ, cnt_dstQ,
                                     (const float4*)x, (uint2*)Xb,
                                     basis0, basis1, basis2, Bt0, Bt1, Bt2);
    k_norms_partial<<<SCB2, 256, 0, stream>>>(cnt_srcQ, cnt_dstQ, nsrc, ndst, cntd2, part);
    k_emit2<<<SCB2, 256, 0, stream>>>(cntd2, part, rp2, gcur);
    k_fillA<<<dim3(EE / CHA, RR), 256, 0, stream>>>(src, dst, gcur, stage);
    k_fillB<<<NBK, 256, 0, stream>>>(stage, rp2, nsrc, ndst, ed);

    int fusedBlocks = (NN + 31) / 32;   // 1563

    // layer 0: Xb -> Hb (relu, bf16)
    k_agg_gemm<128, true><<<fusedBlocks, 512, 0, stream>>>(
        (const uint4*)Xb, rp2, ed, coeff0, Bt0, Hb);
    // layer 1: Hb -> Hb2 (double-buffered: in-place would race)
    k_agg_gemm<128, true><<<fusedBlocks, 512, 0, stream>>>(
        (const uint4*)Hb, rp2, ed, coeff1, Bt1, Hb2);
    // layer 2: Hb2 -> out (fp32, no relu)
    k_agg_gemm<64, false><<<fusedBlocks, 512, 0, stream>>>(
        (const uint4*)Hb2, rp2, ed, coeff2, Bt2, out);
}